// Round 16
// baseline (1158.346 us; speedup 1.0000x reference)
//
#include <hip/hip_runtime.h>
#include <hip/hip_bf16.h>

// GroupedMLP: E=8, T=1024, H=2048, I=5632
// Round 15: r14 fused-B ring-3 with the B-tail DE-SERIALIZED. Per tile:
//   barrier -> vmcnt(2) [B(t+1) regs, loaded a full tile ago: free]
//   writeB(p1)          [overlaps compute issue]
//   loadB(B(t+2)) + stageA(A(t+2))
//   compute(p0)
//   lgkmcnt(0) [write landed long ago] + vmcnt(10) [A(t+1), old: free] + barrier
// r14's serial tail (vmcnt+cvt+ds_write+lgkm between compute and barrier) was
// the +1270cyc/tile regression vs r12. Same geometry: 256x128, BK=32, 8 waves
// of 64x64, 3x24KB LDS, 2 blocks/CU, mt-innermost, G2 swizzle, fused fp32-B.

#define EXPERTS 8
#define TOK     1024
#define HID     2048
#define INTER   5632
#define I2      (2 * INTER)

typedef __bf16 bf16x8 __attribute__((ext_vector_type(8)));
typedef float  f32x4  __attribute__((ext_vector_type(4)));

#define G2(row) ((((row) >> 1) & 3) << 3)   // element-index XOR, bits 3-4

__device__ __forceinline__ unsigned short f2bf(float f) {
    union { float f; unsigned u; } v; v.f = f;
    unsigned r = v.u + 0x7FFFu + ((v.u >> 16) & 1u);   // RNE
    return (unsigned short)(r >> 16);
}

__device__ __forceinline__ void gload_lds16(const void* g, void* l) {
    __builtin_amdgcn_global_load_lds(
        (const __attribute__((address_space(1))) void*)g,
        (__attribute__((address_space(3))) void*)l, 16, 0, 0);
}

// fragment read from a [rows][32] bf16 tile, swizzled by G2(row)
__device__ __forceinline__ bf16x8 ldfrag(const unsigned short* S, int R, int kb) {
    int off = R * 32 + (kb ^ G2(R));
    return *reinterpret_cast<const bf16x8*>(S + off);
}

// ---------------- convert X only (G2-swizzled bf16 ws) ----------------

__global__ __launch_bounds__(256) void k_cvt_x(const float* __restrict__ X,
                                               unsigned short* __restrict__ Xb) {
    size_t base = ((size_t)blockIdx.x * 256 + threadIdx.x) * 8;
    int row = (int)(base >> 11);
    int k   = (int)(base & (HID - 1));
    int kp  = k ^ G2(row);
    float4 v0 = *reinterpret_cast<const float4*>(X + base);
    float4 v1 = *reinterpret_cast<const float4*>(X + base + 4);
    uint4 o;
    o.x = (unsigned)f2bf(v0.x) | ((unsigned)f2bf(v0.y) << 16);
    o.y = (unsigned)f2bf(v0.z) | ((unsigned)f2bf(v0.w) << 16);
    o.z = (unsigned)f2bf(v1.x) | ((unsigned)f2bf(v1.y) << 16);
    o.w = (unsigned)f2bf(v1.z) | ((unsigned)f2bf(v1.w) << 16);
    *reinterpret_cast<uint4*>(Xb + (size_t)row * HID + kp) = o;
}

// ---------------- ring-3 GEMM core, fused fp32 B, write-at-start ----------------
// Buffer (24KB = 12288 ushorts): A [256][32] at 0, B [128][32] at +8192.

template <int KTOT>
__device__ __forceinline__ void stageA(const unsigned short* Ab, int k0,
                                       unsigned short* buf, int t) {
#pragma unroll
    for (int j = 0; j < 2; ++j) {
        int lin = j * 512 + t;
        int row = lin >> 2;
        int col = (lin & 3) * 8;
        gload_lds16(Ab + (size_t)row * KTOT + k0 + col, buf + lin * 8);
    }
}

__device__ __forceinline__ void loadB(const float* W, size_t ldw, int gcol, int k0,
                                      int kq8, float (&r)[8]) {
    const float* p = W + (size_t)(k0 + kq8) * ldw + gcol;
#pragma unroll
    for (int j = 0; j < 8; ++j) r[j] = p[j * ldw];
}

__device__ __forceinline__ void writeB(unsigned short* Bl, int pcl, int kq8,
                                       float (&r)[8]) {
    uint4 o;
    o.x = (unsigned)f2bf(r[0]) | ((unsigned)f2bf(r[1]) << 16);
    o.y = (unsigned)f2bf(r[2]) | ((unsigned)f2bf(r[3]) << 16);
    o.z = (unsigned)f2bf(r[4]) | ((unsigned)f2bf(r[5]) << 16);
    o.w = (unsigned)f2bf(r[6]) | ((unsigned)f2bf(r[7]) << 16);
    *reinterpret_cast<uint4*>(Bl + pcl * 32 + (kq8 ^ G2(pcl))) = o;
}

#define MFMA_BF16(a, b, c) __builtin_amdgcn_mfma_f32_16x16x32_bf16(a, b, c, 0, 0, 0)

__device__ __forceinline__ void compute_tile(const unsigned short* Ac,
                                             const unsigned short* Bc,
                                             f32x4 (&acc)[4][4],
                                             int wr, int wc, int cl, int kb0) {
    bf16x8 b[4], a[2];
#pragma unroll
    for (int n = 0; n < 4; ++n)
        b[n] = ldfrag(Bc, wc + n * 16 + cl, kb0);
    a[0] = ldfrag(Ac, wr + cl, kb0);
#pragma unroll
    for (int m = 0; m < 4; ++m) {
        if (m < 3)
            a[(m + 1) & 1] = ldfrag(Ac, wr + (m + 1) * 16 + cl, kb0);
        __builtin_amdgcn_s_setprio(1);
#pragma unroll
        for (int n = 0; n < 4; ++n)
            acc[m][n] = MFMA_BF16(a[m & 1], b[n], acc[m][n]);
        __builtin_amdgcn_s_setprio(0);
    }
}

template <int KTOT>
__device__ __forceinline__ void gemm_ring3(const unsigned short* Ab, const float* W,
                                           size_t ldw, int gcol, int pcl,
                                           f32x4 (&acc)[4][4],
                                           unsigned short* lds, int t, int lane,
                                           int wr, int wc) {
    const int cl  = lane & 15;
    const int kb0 = (lane >> 4) << 3;
    const int kq8 = (t >> 7) * 8;
    const int nkt = KTOT / 32;

    unsigned short* bufs[3] = { lds, lds + 12288, lds + 24576 };

    float rA[8];
    // prologue: B(0)->regs, A(0)->buf0; drain; B(0)->LDS; B(1)->regs, A(1)->buf1
    loadB(W, ldw, gcol, 0, kq8, rA);
    stageA<KTOT>(Ab, 0, bufs[0], t);
    asm volatile("s_waitcnt vmcnt(0)" ::: "memory");
    writeB(bufs[0] + 8192, pcl, kq8, rA);
    loadB(W, ldw, gcol, 32, kq8, rA);
    stageA<KTOT>(Ab, 32, bufs[1], t);
    asm volatile("s_waitcnt lgkmcnt(0)" ::: "memory");
    __builtin_amdgcn_s_barrier();
    asm volatile("" ::: "memory");
    // loop entry outstanding: B(1) x8 (older), A(1) x2 (newer)

    int c0 = 0;
    for (int kt = 0; kt < nkt; ++kt) {
        unsigned short* p0 = bufs[c0];
        unsigned short* p1 = bufs[c0 == 2 ? 0 : c0 + 1];
        unsigned short* p2 = bufs[c0 == 0 ? 2 : c0 - 1];

        // head: B(t+1) regs ready (loaded a full tile ago) -> write to p1.B now
        if (kt + 1 < nkt) {
            asm volatile("s_waitcnt vmcnt(2)" ::: "memory");  // keep A(t+1) in flight
            writeB(p1 + 8192, pcl, kq8, rA);
        }
        // issue-early: B(t+2) regs + A(t+2) glds
        if (kt + 2 < nkt) {
            loadB(W, ldw, gcol, (kt + 2) * 32, kq8, rA);      // WAR on rA: reg deps
            stageA<KTOT>(Ab, (kt + 2) * 32, p2, t);
        }

        compute_tile(p0, p0 + 8192, acc, wr, wc, cl, kb0);

        // tail: all waits are on old ops -> ~free; single barrier
        if (kt + 1 < nkt) {
            asm volatile("s_waitcnt lgkmcnt(0)" ::: "memory");
            if (kt + 2 < nkt) { asm volatile("s_waitcnt vmcnt(10)" ::: "memory"); }
            else              { asm volatile("s_waitcnt vmcnt(0)"  ::: "memory"); }
            __builtin_amdgcn_s_barrier();
            asm volatile("" ::: "memory");
        }
        c0 = (c0 == 2) ? 0 : c0 + 1;
    }
}

// fc1: Xb(bf16 ws) @ w1(fp32 native [H][2I]) -> inter bf16 (GLU fused)
__global__ __launch_bounds__(512, 4) void k_fc1_r5(const unsigned short* __restrict__ Xb,
                                                   const float* __restrict__ W1,
                                                   unsigned short* __restrict__ inter) {
    extern __shared__ unsigned short lds[];
    const int bid = blockIdx.x;                // 2816 = 8 XCD * (4 mt * 88 nt)
    const int e   = bid & 7;
    const int idx = bid >> 3;
    const int mt  = idx & 3;                   // mt innermost: B-panel shared
    const int nt  = idx >> 2;                  // 0..87
    const int t = threadIdx.x, lane = t & 63, w = t >> 6;
    const int wr = (w >> 1) * 64;
    const int wc = (w & 1) * 64;
    const int m0 = e * TOK + mt * 256;
    const int n0 = nt * 128;                   // pc-space
    const unsigned short* Ab = Xb + (size_t)m0 * HID;
    const float* W = W1 + (size_t)e * HID * I2;
    // coalesced load mapping decoupled from LDS row (threads 0-63: 'a' cols,
    // 64-127: 'b' cols); LDS row = GLU-interleaved pc
    const int tc   = t & 127;
    const int nh   = n0 >> 1;
    const int gcol = (tc < 64) ? (nh + tc) : (INTER + nh + (tc - 64));
    const int pcl  = (tc < 64) ? (2 * tc) : (2 * (tc - 64) + 1);

    f32x4 acc[4][4];
#pragma unroll
    for (int i = 0; i < 4; ++i)
#pragma unroll
        for (int j = 0; j < 4; ++j) acc[i][j] = f32x4{0.f, 0.f, 0.f, 0.f};

    gemm_ring3<HID>(Ab, W, (size_t)I2, gcol, pcl, acc, lds, t, lane, wr, wc);

    const int cl = lane & 15;
    const int r0 = (lane >> 4) << 2;
#pragma unroll
    for (int mf = 0; mf < 4; ++mf)
#pragma unroll
        for (int nf = 0; nf < 4; ++nf)
#pragma unroll
            for (int r = 0; r < 4; ++r) {
                float v  = acc[mf][nf][r];
                float pv = __shfl_xor(v, 1);
                if ((lane & 1) == 0) {
                    float s = v / (1.f + __expf(-v)) * pv;
                    int row = m0 + wr + mf * 16 + r0 + r;
                    int pcc = n0 + wc + nf * 16 + cl;
                    int c   = pcc >> 1;
                    int c2  = (c & ~31) | ((c & 31) ^ G2(row));  // fc2-A swizzle
                    inter[(size_t)row * INTER + c2] = f2bf(s);
                }
            }
}

// fc2: inter(bf16 ws) @ w2(fp32 native [I][H]) -> out fp32
__global__ __launch_bounds__(512, 4) void k_fc2_r5(const unsigned short* __restrict__ A,
                                                   const float* __restrict__ W2,
                                                   float* __restrict__ out) {
    extern __shared__ unsigned short lds[];
    const int bid = blockIdx.x;                // 512 = 8 XCD * (4 mt * 16 nt)
    const int e   = bid & 7;
    const int idx = bid >> 3;
    const int mt  = idx & 3;
    const int nt  = idx >> 2;                  // 0..15
    const int t = threadIdx.x, lane = t & 63, w = t >> 6;
    const int wr = (w >> 1) * 64;
    const int wc = (w & 1) * 64;
    const int m0 = e * TOK + mt * 256;
    const int n0 = nt * 128;
    const unsigned short* Ab = A + (size_t)m0 * INTER;
    const float* W = W2 + (size_t)e * INTER * HID;
    const int tc   = t & 127;
    const int gcol = n0 + tc;
    const int pcl  = tc;

    f32x4 acc[4][4];
#pragma unroll
    for (int i = 0; i < 4; ++i)
#pragma unroll
        for (int j = 0; j < 4; ++j) acc[i][j] = f32x4{0.f, 0.f, 0.f, 0.f};

    gemm_ring3<INTER>(Ab, W, (size_t)HID, gcol, pcl, acc, lds, t, lane, wr, wc);

    const int cl = lane & 15;
    const int r0 = (lane >> 4) << 2;
#pragma unroll
    for (int mf = 0; mf < 4; ++mf)
#pragma unroll
        for (int nf = 0; nf < 4; ++nf)
#pragma unroll
            for (int r = 0; r < 4; ++r) {
                int row = m0 + wr + mf * 16 + r0 + r;
                int col = n0 + wc + nf * 16 + cl;
                out[(size_t)row * HID + col] = acc[mf][nf][r];
            }
}

// ---------------- fallback (round-1 kernels, need only 92 MB ws) ----------------

#define BM  128
#define BK  64
#define LDK 72

__global__ __launch_bounds__(256) void k_fc1_glu_fb(
    const float* __restrict__ X, const float* __restrict__ W1,
    unsigned short* __restrict__ inter)
{
    __shared__ unsigned short As[BM][LDK];
    __shared__ unsigned short Bs[128][LDK];
    const int bid = blockIdx.x;
    const int nt  = bid % (INTER / 64);
    const int mt  = (bid / (INTER / 64)) % (TOK / BM);
    const int e   = bid / ((INTER / 64) * (TOK / BM));
    const int t = threadIdx.x, lane = t & 63, w = t >> 6;
    const int m0 = mt * BM;
    const int rowbase = e * TOK + m0;
    f32x4 acc[2][8];
#pragma unroll
    for (int i = 0; i < 2; ++i)
#pragma unroll
        for (int jj = 0; jj < 8; ++jj) acc[i][jj] = f32x4{0.f, 0.f, 0.f, 0.f};
    const int jcol = t & 127;
    const int hf   = t >> 7;
    const int gcol = (jcol < 64) ? (nt * 64 + jcol) : (INTER + nt * 64 + (jcol - 64));
    const float* w1e = W1 + (size_t)e * HID * I2;
    for (int k0 = 0; k0 < HID; k0 += BK) {
#pragma unroll
        for (int it = 0; it < 8; ++it) {
            int lin = it * 256 + t;
            int r   = lin >> 4;
            int kq  = (lin & 15) << 2;
            const float4 v = *reinterpret_cast<const float4*>(
                X + (size_t)(rowbase + r) * HID + k0 + kq);
            ushort4 o;
            o.x = f2bf(v.x); o.y = f2bf(v.y); o.z = f2bf(v.z); o.w = f2bf(v.w);
            *reinterpret_cast<ushort4*>(&As[r][kq]) = o;
        }
#pragma unroll
        for (int it = 0; it < 8; ++it) {
            int kq = hf * 4 + it * 8;
            const float* p = w1e + (size_t)(k0 + kq) * I2 + gcol;
            float v0 = p[0], v1 = p[I2], v2 = p[2 * I2], v3 = p[3 * I2];
            ushort4 o;
            o.x = f2bf(v0); o.y = f2bf(v1); o.z = f2bf(v2); o.w = f2bf(v3);
            *reinterpret_cast<ushort4*>(&Bs[jcol][kq]) = o;
        }
        __syncthreads();
#pragma unroll
        for (int kk = 0; kk < 2; ++kk) {
            const int kb = kk * 32 + ((lane >> 4) << 3);
            bf16x8 a0 = *reinterpret_cast<const bf16x8*>(&As[w * 32 + (lane & 15)][kb]);
            bf16x8 a1 = *reinterpret_cast<const bf16x8*>(&As[w * 32 + 16 + (lane & 15)][kb]);
#pragma unroll
            for (int nf = 0; nf < 8; ++nf) {
                bf16x8 b = *reinterpret_cast<const bf16x8*>(&Bs[nf * 16 + (lane & 15)][kb]);
                acc[0][nf] = MFMA_BF16(a0, b, acc[0][nf]);
                acc[1][nf] = MFMA_BF16(a1, b, acc[1][nf]);
            }
        }
        __syncthreads();
    }
    const int rl0 = w * 32 + ((lane >> 4) << 2);
    const int cl  = lane & 15;
#pragma unroll
    for (int mf = 0; mf < 2; ++mf)
#pragma unroll
        for (int nfa = 0; nfa < 4; ++nfa) {
            f32x4 va = acc[mf][nfa];
            f32x4 vb = acc[mf][nfa + 4];
#pragma unroll
            for (int r = 0; r < 4; ++r) {
                float a = va[r], b = vb[r];
                float s = a / (1.f + __expf(-a)) * b;
                int row = rowbase + rl0 + mf * 16 + r;
                int col = nt * 64 + nfa * 16 + cl;
                inter[(size_t)row * INTER + col] = f2bf(s);
            }
        }
}

__global__ __launch_bounds__(256) void k_fc2_fb(
    const unsigned short* __restrict__ inter, const float* __restrict__ W2,
    float* __restrict__ out)
{
    __shared__ unsigned short As[BM][LDK];
    __shared__ unsigned short Bs[128][LDK];
    const int bid = blockIdx.x;
    const int nt  = bid % (HID / 128);
    const int mt  = (bid / (HID / 128)) % (TOK / BM);
    const int e   = bid / ((HID / 128) * (TOK / BM));
    const int t = threadIdx.x, lane = t & 63, w = t >> 6;
    const int m0 = mt * BM;
    const int rowbase = e * TOK + m0;
    f32x4 acc[2][8];
#pragma unroll
    for (int i = 0; i < 2; ++i)
#pragma unroll
        for (int jj = 0; jj < 8; ++jj) acc[i][jj] = f32x4{0.f, 0.f, 0.f, 0.f};
    const int jcol = t & 127;
    const int hf   = t >> 7;
    const int gcol = nt * 128 + jcol;
    const float* w2e = W2 + (size_t)e * INTER * HID;
    for (int k0 = 0; k0 < INTER; k0 += BK) {
#pragma unroll
        for (int it = 0; it < 4; ++it) {
            int lin = it * 256 + t;
            int r   = lin >> 3;
            int kq  = (lin & 7) << 3;
            uint4 v = *reinterpret_cast<const uint4*>(
                inter + (size_t)(rowbase + r) * INTER + k0 + kq);
            *reinterpret_cast<uint4*>(&As[r][kq]) = v;
        }
#pragma unroll
        for (int it = 0; it < 8; ++it) {
            int kq = hf * 4 + it * 8;
            const float* p = w2e + (size_t)(k0 + kq) * HID + gcol;
            float v0 = p[0], v1 = p[HID], v2 = p[2 * HID], v3 = p[3 * HID];
            ushort4 o;
            o.x = f2bf(v0); o.y = f2bf(v1); o.z = f2bf(v2); o.w = f2bf(v3);
            *reinterpret_cast<ushort4*>(&Bs[jcol][kq]) = o;
        }
        __syncthreads();
#pragma unroll
        for (int kk = 0; kk < 2; ++kk) {
            const int kb = kk * 32 + ((lane >> 4) << 3);
            bf16x8 a0 = *reinterpret_cast<const bf16x8*>(&As[w * 32 + (lane & 15)][kb]);
            bf16x8 a1 = *reinterpret_cast<const bf16x8*>(&As[w * 32 + 16 + (lane & 15)][kb]);
#pragma unroll
            for (int nf = 0; nf < 8; ++nf) {
                bf16x8 b = *reinterpret_cast<const bf16x8*>(&Bs[nf * 16 + (lane & 15)][kb]);
                acc[0][nf] = MFMA_BF16(a0, b, acc[0][nf]);
                acc[1][nf] = MFMA_BF16(a1, b, acc[1][nf]);
            }
        }
        __syncthreads();
    }
    const int rl0 = w * 32 + ((lane >> 4) << 2);
    const int cl  = lane & 15;
#pragma unroll
    for (int mf = 0; mf < 2; ++mf)
#pragma unroll
        for (int nf = 0; nf < 8; ++nf) {
            f32x4 v = acc[mf][nf];
#pragma unroll
            for (int r = 0; r < 4; ++r) {
                int row = rowbase + rl0 + mf * 16 + r;
                int col = nt * 128 + nf * 16 + cl;
                out[(size_t)row * HID + col] = v[r];
            }
        }
}

// ---------------- launch ----------------

extern "C" void kernel_launch(void* const* d_in, const int* in_sizes, int n_in,
                              void* d_out, int out_size, void* d_ws, size_t ws_size,
                              hipStream_t stream) {
    const float* X  = (const float*)d_in[0];
    const float* W1 = (const float*)d_in[1];
    const float* W2 = (const float*)d_in[2];
    float* out = (float*)d_out;

    const size_t XB_B  = (size_t)EXPERTS * TOK * HID * 2;        // 33.5 MB
    const size_t INT_B = (size_t)EXPERTS * TOK * INTER * 2;      // 92.3 MB
    const size_t need  = XB_B + INT_B;

    if (ws_size >= need) {
        unsigned short* Xb    = (unsigned short*)d_ws;
        unsigned short* inter = (unsigned short*)((char*)d_ws + XB_B);

        hipFuncSetAttribute((const void*)k_fc1_r5,
            hipFuncAttributeMaxDynamicSharedMemorySize, 73728);
        hipFuncSetAttribute((const void*)k_fc2_r5,
            hipFuncAttributeMaxDynamicSharedMemorySize, 73728);

        dim3 b256(256), b512(512);
        k_cvt_x <<<(EXPERTS * TOK * HID) / (256 * 8), b256, 0, stream>>>(X, Xb);
        k_fc1_r5<<<EXPERTS * 4 * (I2 / 128),  b512, 73728, stream>>>(Xb, W1, inter);
        k_fc2_r5<<<EXPERTS * 4 * (HID / 128), b512, 73728, stream>>>(inter, W2, out);
    } else {
        unsigned short* inter = (unsigned short*)d_ws;
        dim3 b256(256);
        k_fc1_glu_fb<<<EXPERTS * (TOK / BM) * (INTER / 64), b256, 0, stream>>>(X, W1, inter);
        k_fc2_fb    <<<EXPERTS * (TOK / BM) * (HID / 128),  b256, 0, stream>>>(inter, W2, out);
    }
}

// Round 17
// 859.741 us; speedup vs baseline: 1.3473x; 1.3473x over previous
//
#include <hip/hip_runtime.h>
#include <hip/hip_bf16.h>

// GroupedMLP: E=8, T=1024, H=2048, I=5632
// Round 16: r14 base (best total 852us) + ONE change: 2-deep B-register
// prefetch. r14's only non-free wait was tail vmcnt(2) on B(t+1) loaded at
// the SAME tile's top. Now rB0/rB1 double-buffer: tile t top loads B(t+2),
// tail waits vmcnt(10) on B(t+1)/A(t+1) issued a full tile earlier (~free).
// Loop unrolled by 2 with NAMED register sets (rule #20: no runtime-indexed
// reg arrays). Everything else r14-verbatim: ring-3 24KB bufs, 256x128 BK=32,
// 8 waves of 64x64, 2 blocks/CU, G2 swizzle, mt-innermost, fused fp32-B,
// write-at-tail, stageA 2-ahead via global_load_lds.

#define EXPERTS 8
#define TOK     1024
#define HID     2048
#define INTER   5632
#define I2      (2 * INTER)

typedef __bf16 bf16x8 __attribute__((ext_vector_type(8)));
typedef float  f32x4  __attribute__((ext_vector_type(4)));

#define G2(row) ((((row) >> 1) & 3) << 3)   // element-index XOR, bits 3-4

__device__ __forceinline__ unsigned short f2bf(float f) {
    union { float f; unsigned u; } v; v.f = f;
    unsigned r = v.u + 0x7FFFu + ((v.u >> 16) & 1u);   // RNE
    return (unsigned short)(r >> 16);
}

__device__ __forceinline__ void gload_lds16(const void* g, void* l) {
    __builtin_amdgcn_global_load_lds(
        (const __attribute__((address_space(1))) void*)g,
        (__attribute__((address_space(3))) void*)l, 16, 0, 0);
}

// fragment read from a [rows][32] bf16 tile, swizzled by G2(row)
__device__ __forceinline__ bf16x8 ldfrag(const unsigned short* S, int R, int kb) {
    int off = R * 32 + (kb ^ G2(R));
    return *reinterpret_cast<const bf16x8*>(S + off);
}

// ---------------- convert X only (G2-swizzled bf16 ws) ----------------

__global__ __launch_bounds__(256) void k_cvt_x(const float* __restrict__ X,
                                               unsigned short* __restrict__ Xb) {
    size_t base = ((size_t)blockIdx.x * 256 + threadIdx.x) * 8;
    int row = (int)(base >> 11);
    int k   = (int)(base & (HID - 1));
    int kp  = k ^ G2(row);
    float4 v0 = *reinterpret_cast<const float4*>(X + base);
    float4 v1 = *reinterpret_cast<const float4*>(X + base + 4);
    uint4 o;
    o.x = (unsigned)f2bf(v0.x) | ((unsigned)f2bf(v0.y) << 16);
    o.y = (unsigned)f2bf(v0.z) | ((unsigned)f2bf(v0.w) << 16);
    o.z = (unsigned)f2bf(v1.x) | ((unsigned)f2bf(v1.y) << 16);
    o.w = (unsigned)f2bf(v1.z) | ((unsigned)f2bf(v1.w) << 16);
    *reinterpret_cast<uint4*>(Xb + (size_t)row * HID + kp) = o;
}

// ---------------- ring-3 GEMM core, fused fp32 B, 2-deep B prefetch ----------
// Buffer (24KB = 12288 ushorts): A [256][32] at 0, B [128][32] at +8192.

template <int KTOT>
__device__ __forceinline__ void stageA(const unsigned short* Ab, int k0,
                                       unsigned short* buf, int t) {
#pragma unroll
    for (int j = 0; j < 2; ++j) {
        int lin = j * 512 + t;
        int row = lin >> 2;
        int col = (lin & 3) * 8;
        gload_lds16(Ab + (size_t)row * KTOT + k0 + col, buf + lin * 8);
    }
}

__device__ __forceinline__ void loadB(const float* W, size_t ldw, int gcol, int k0,
                                      int kq8, float (&r)[8]) {
    const float* p = W + (size_t)(k0 + kq8) * ldw + gcol;
#pragma unroll
    for (int j = 0; j < 8; ++j) r[j] = p[j * ldw];
}

__device__ __forceinline__ void writeB(unsigned short* Bl, int pcl, int kq8,
                                       float (&r)[8]) {
    uint4 o;
    o.x = (unsigned)f2bf(r[0]) | ((unsigned)f2bf(r[1]) << 16);
    o.y = (unsigned)f2bf(r[2]) | ((unsigned)f2bf(r[3]) << 16);
    o.z = (unsigned)f2bf(r[4]) | ((unsigned)f2bf(r[5]) << 16);
    o.w = (unsigned)f2bf(r[6]) | ((unsigned)f2bf(r[7]) << 16);
    *reinterpret_cast<uint4*>(Bl + pcl * 32 + (kq8 ^ G2(pcl))) = o;
}

#define MFMA_BF16(a, b, c) __builtin_amdgcn_mfma_f32_16x16x32_bf16(a, b, c, 0, 0, 0)

__device__ __forceinline__ void compute_tile(const unsigned short* Ac,
                                             const unsigned short* Bc,
                                             f32x4 (&acc)[4][4],
                                             int wr, int wc, int cl, int kb0) {
    bf16x8 b[4], a[2];
#pragma unroll
    for (int n = 0; n < 4; ++n)
        b[n] = ldfrag(Bc, wc + n * 16 + cl, kb0);
    a[0] = ldfrag(Ac, wr + cl, kb0);
#pragma unroll
    for (int m = 0; m < 4; ++m) {
        if (m < 3)
            a[(m + 1) & 1] = ldfrag(Ac, wr + (m + 1) * 16 + cl, kb0);
        __builtin_amdgcn_s_setprio(1);
#pragma unroll
        for (int n = 0; n < 4; ++n)
            acc[m][n] = MFMA_BF16(a[m & 1], b[n], acc[m][n]);
        __builtin_amdgcn_s_setprio(0);
    }
}

// one ring step: issue B(kt+2)->rLoad + A(kt+2)->p2, compute p0,
// tail: vmcnt(free) + writeB(p1, rWrite) + lgkm + barrier
template <int KTOT>
__device__ __forceinline__ void ring_step(const unsigned short* Ab, const float* W,
                                          size_t ldw, int gcol, int pcl, int kq8,
                                          float (&rLoad)[8], float (&rWrite)[8],
                                          int kt, int nkt,
                                          unsigned short* p0, unsigned short* p1,
                                          unsigned short* p2,
                                          f32x4 (&acc)[4][4], int t,
                                          int wr, int wc, int cl, int kb0) {
    if (kt + 2 < nkt) {
        loadB(W, ldw, gcol, (kt + 2) * 32, kq8, rLoad);
        stageA<KTOT>(Ab, (kt + 2) * 32, p2, t);
    }
    compute_tile(p0, p0 + 8192, acc, wr, wc, cl, kb0);
    if (kt + 1 < nkt) {
        // drains B(kt+1)+A(kt+1) (issued a full tile ago); keeps (kt+2) set in flight
        if (kt + 2 < nkt) { asm volatile("s_waitcnt vmcnt(10)" ::: "memory"); }
        else              { asm volatile("s_waitcnt vmcnt(0)"  ::: "memory"); }
        writeB(p1 + 8192, pcl, kq8, rWrite);
        asm volatile("s_waitcnt lgkmcnt(0)" ::: "memory");
        __builtin_amdgcn_s_barrier();
        asm volatile("" ::: "memory");
    }
}

template <int KTOT>
__device__ __forceinline__ void gemm_ring3(const unsigned short* Ab, const float* W,
                                           size_t ldw, int gcol, int pcl,
                                           f32x4 (&acc)[4][4],
                                           unsigned short* lds, int t, int lane,
                                           int wr, int wc) {
    const int cl  = lane & 15;
    const int kb0 = (lane >> 4) << 3;
    const int kq8 = (t >> 7) * 8;
    const int nkt = KTOT / 32;   // even for both GEMMs (64, 176)

    unsigned short* b0 = lds;
    unsigned short* b1 = lds + 12288;
    unsigned short* b2 = lds + 24576;

    float rB0[8], rB1[8];
    // prologue: B(0),A(0),B(1),A(1); vmcnt(10) drains B(0)+A(0); write B(0)
    loadB(W, ldw, gcol, 0, kq8, rB0);
    stageA<KTOT>(Ab, 0, b0, t);
    loadB(W, ldw, gcol, 32, kq8, rB1);
    stageA<KTOT>(Ab, 32, b1, t);
    asm volatile("s_waitcnt vmcnt(10)" ::: "memory");
    writeB(b0 + 8192, pcl, kq8, rB0);
    asm volatile("s_waitcnt lgkmcnt(0)" ::: "memory");
    __builtin_amdgcn_s_barrier();
    asm volatile("" ::: "memory");
    // entering tile 0: outstanding = B(1)x8 + A(1)x2; rB1 = B(1) regs

    for (int kt = 0; kt < nkt; kt += 2) {
        // even tile kt: load target rB0 (=B(kt+2)), write source rB1 (=B(kt+1))
        ring_step<KTOT>(Ab, W, ldw, gcol, pcl, kq8, rB0, rB1,
                        kt, nkt, b0, b1, b2, acc, t, wr, wc, cl, kb0);
        // odd tile kt+1: load target rB1, write source rB0
        ring_step<KTOT>(Ab, W, ldw, gcol, pcl, kq8, rB1, rB0,
                        kt + 1, nkt, b1, b2, b0, acc, t, wr, wc, cl, kb0);
        // rotate ring by 2
        unsigned short* tmp = b0; b0 = b2; b2 = b1; b1 = tmp;
    }
}

// fc1: Xb(bf16 ws) @ w1(fp32 native [H][2I]) -> inter bf16 (GLU fused)
__global__ __launch_bounds__(512, 4) void k_fc1_r6(const unsigned short* __restrict__ Xb,
                                                   const float* __restrict__ W1,
                                                   unsigned short* __restrict__ inter) {
    extern __shared__ unsigned short lds[];
    const int bid = blockIdx.x;                // 2816 = 8 XCD * (4 mt * 88 nt)
    const int e   = bid & 7;
    const int idx = bid >> 3;
    const int mt  = idx & 3;                   // mt innermost: B-panel shared
    const int nt  = idx >> 2;                  // 0..87
    const int t = threadIdx.x, lane = t & 63, w = t >> 6;
    const int wr = (w >> 1) * 64;
    const int wc = (w & 1) * 64;
    const int m0 = e * TOK + mt * 256;
    const int n0 = nt * 128;                   // pc-space
    const unsigned short* Ab = Xb + (size_t)m0 * HID;
    const float* W = W1 + (size_t)e * HID * I2;
    // coalesced load mapping decoupled from LDS row (threads 0-63: 'a' cols,
    // 64-127: 'b' cols); LDS row = GLU-interleaved pc
    const int tc   = t & 127;
    const int nh   = n0 >> 1;
    const int gcol = (tc < 64) ? (nh + tc) : (INTER + nh + (tc - 64));
    const int pcl  = (tc < 64) ? (2 * tc) : (2 * (tc - 64) + 1);

    f32x4 acc[4][4];
#pragma unroll
    for (int i = 0; i < 4; ++i)
#pragma unroll
        for (int j = 0; j < 4; ++j) acc[i][j] = f32x4{0.f, 0.f, 0.f, 0.f};

    gemm_ring3<HID>(Ab, W, (size_t)I2, gcol, pcl, acc, lds, t, lane, wr, wc);

    const int cl = lane & 15;
    const int r0 = (lane >> 4) << 2;
#pragma unroll
    for (int mf = 0; mf < 4; ++mf)
#pragma unroll
        for (int nf = 0; nf < 4; ++nf)
#pragma unroll
            for (int r = 0; r < 4; ++r) {
                float v  = acc[mf][nf][r];
                float pv = __shfl_xor(v, 1);
                if ((lane & 1) == 0) {
                    float s = v / (1.f + __expf(-v)) * pv;
                    int row = m0 + wr + mf * 16 + r0 + r;
                    int pcc = n0 + wc + nf * 16 + cl;
                    int c   = pcc >> 1;
                    int c2  = (c & ~31) | ((c & 31) ^ G2(row));  // fc2-A swizzle
                    inter[(size_t)row * INTER + c2] = f2bf(s);
                }
            }
}

// fc2: inter(bf16 ws) @ w2(fp32 native [I][H]) -> out fp32
__global__ __launch_bounds__(512, 4) void k_fc2_r6(const unsigned short* __restrict__ A,
                                                   const float* __restrict__ W2,
                                                   float* __restrict__ out) {
    extern __shared__ unsigned short lds[];
    const int bid = blockIdx.x;                // 512 = 8 XCD * (4 mt * 16 nt)
    const int e   = bid & 7;
    const int idx = bid >> 3;
    const int mt  = idx & 3;
    const int nt  = idx >> 2;                  // 0..15
    const int t = threadIdx.x, lane = t & 63, w = t >> 6;
    const int wr = (w >> 1) * 64;
    const int wc = (w & 1) * 64;
    const int m0 = e * TOK + mt * 256;
    const int n0 = nt * 128;
    const unsigned short* Ab = A + (size_t)m0 * INTER;
    const float* W = W2 + (size_t)e * INTER * HID;
    const int tc   = t & 127;
    const int gcol = n0 + tc;
    const int pcl  = tc;

    f32x4 acc[4][4];
#pragma unroll
    for (int i = 0; i < 4; ++i)
#pragma unroll
        for (int j = 0; j < 4; ++j) acc[i][j] = f32x4{0.f, 0.f, 0.f, 0.f};

    gemm_ring3<INTER>(Ab, W, (size_t)HID, gcol, pcl, acc, lds, t, lane, wr, wc);

    const int cl = lane & 15;
    const int r0 = (lane >> 4) << 2;
#pragma unroll
    for (int mf = 0; mf < 4; ++mf)
#pragma unroll
        for (int nf = 0; nf < 4; ++nf)
#pragma unroll
            for (int r = 0; r < 4; ++r) {
                int row = m0 + wr + mf * 16 + r0 + r;
                int col = n0 + wc + nf * 16 + cl;
                out[(size_t)row * HID + col] = acc[mf][nf][r];
            }
}

// ---------------- fallback (round-1 kernels, need only 92 MB ws) ----------------

#define BM  128
#define BK  64
#define LDK 72

__global__ __launch_bounds__(256) void k_fc1_glu_fb(
    const float* __restrict__ X, const float* __restrict__ W1,
    unsigned short* __restrict__ inter)
{
    __shared__ unsigned short As[BM][LDK];
    __shared__ unsigned short Bs[128][LDK];
    const int bid = blockIdx.x;
    const int nt  = bid % (INTER / 64);
    const int mt  = (bid / (INTER / 64)) % (TOK / BM);
    const int e   = bid / ((INTER / 64) * (TOK / BM));
    const int t = threadIdx.x, lane = t & 63, w = t >> 6;
    const int m0 = mt * BM;
    const int rowbase = e * TOK + m0;
    f32x4 acc[2][8];
#pragma unroll
    for (int i = 0; i < 2; ++i)
#pragma unroll
        for (int jj = 0; jj < 8; ++jj) acc[i][jj] = f32x4{0.f, 0.f, 0.f, 0.f};
    const int jcol = t & 127;
    const int hf   = t >> 7;
    const int gcol = (jcol < 64) ? (nt * 64 + jcol) : (INTER + nt * 64 + (jcol - 64));
    const float* w1e = W1 + (size_t)e * HID * I2;
    for (int k0 = 0; k0 < HID; k0 += BK) {
#pragma unroll
        for (int it = 0; it < 8; ++it) {
            int lin = it * 256 + t;
            int r   = lin >> 4;
            int kq  = (lin & 15) << 2;
            const float4 v = *reinterpret_cast<const float4*>(
                X + (size_t)(rowbase + r) * HID + k0 + kq);
            ushort4 o;
            o.x = f2bf(v.x); o.y = f2bf(v.y); o.z = f2bf(v.z); o.w = f2bf(v.w);
            *reinterpret_cast<ushort4*>(&As[r][kq]) = o;
        }
#pragma unroll
        for (int it = 0; it < 8; ++it) {
            int kq = hf * 4 + it * 8;
            const float* p = w1e + (size_t)(k0 + kq) * I2 + gcol;
            float v0 = p[0], v1 = p[I2], v2 = p[2 * I2], v3 = p[3 * I2];
            ushort4 o;
            o.x = f2bf(v0); o.y = f2bf(v1); o.z = f2bf(v2); o.w = f2bf(v3);
            *reinterpret_cast<ushort4*>(&Bs[jcol][kq]) = o;
        }
        __syncthreads();
#pragma unroll
        for (int kk = 0; kk < 2; ++kk) {
            const int kb = kk * 32 + ((lane >> 4) << 3);
            bf16x8 a0 = *reinterpret_cast<const bf16x8*>(&As[w * 32 + (lane & 15)][kb]);
            bf16x8 a1 = *reinterpret_cast<const bf16x8*>(&As[w * 32 + 16 + (lane & 15)][kb]);
#pragma unroll
            for (int nf = 0; nf < 8; ++nf) {
                bf16x8 b = *reinterpret_cast<const bf16x8*>(&Bs[nf * 16 + (lane & 15)][kb]);
                acc[0][nf] = MFMA_BF16(a0, b, acc[0][nf]);
                acc[1][nf] = MFMA_BF16(a1, b, acc[1][nf]);
            }
        }
        __syncthreads();
    }
    const int rl0 = w * 32 + ((lane >> 4) << 2);
    const int cl  = lane & 15;
#pragma unroll
    for (int mf = 0; mf < 2; ++mf)
#pragma unroll
        for (int nfa = 0; nfa < 4; ++nfa) {
            f32x4 va = acc[mf][nfa];
            f32x4 vb = acc[mf][nfa + 4];
#pragma unroll
            for (int r = 0; r < 4; ++r) {
                float a = va[r], b = vb[r];
                float s = a / (1.f + __expf(-a)) * b;
                int row = rowbase + rl0 + mf * 16 + r;
                int col = nt * 64 + nfa * 16 + cl;
                inter[(size_t)row * INTER + col] = f2bf(s);
            }
        }
}

__global__ __launch_bounds__(256) void k_fc2_fb(
    const unsigned short* __restrict__ inter, const float* __restrict__ W2,
    float* __restrict__ out)
{
    __shared__ unsigned short As[BM][LDK];
    __shared__ unsigned short Bs[128][LDK];
    const int bid = blockIdx.x;
    const int nt  = bid % (HID / 128);
    const int mt  = (bid / (HID / 128)) % (TOK / BM);
    const int e   = bid / ((HID / 128) * (TOK / BM));
    const int t = threadIdx.x, lane = t & 63, w = t >> 6;
    const int m0 = mt * BM;
    const int rowbase = e * TOK + m0;
    f32x4 acc[2][8];
#pragma unroll
    for (int i = 0; i < 2; ++i)
#pragma unroll
        for (int jj = 0; jj < 8; ++jj) acc[i][jj] = f32x4{0.f, 0.f, 0.f, 0.f};
    const int jcol = t & 127;
    const int hf   = t >> 7;
    const int gcol = nt * 128 + jcol;
    const float* w2e = W2 + (size_t)e * INTER * HID;
    for (int k0 = 0; k0 < INTER; k0 += BK) {
#pragma unroll
        for (int it = 0; it < 4; ++it) {
            int lin = it * 256 + t;
            int r   = lin >> 3;
            int kq  = (lin & 7) << 3;
            uint4 v = *reinterpret_cast<const uint4*>(
                inter + (size_t)(rowbase + r) * INTER + k0 + kq);
            *reinterpret_cast<uint4*>(&As[r][kq]) = v;
        }
#pragma unroll
        for (int it = 0; it < 8; ++it) {
            int kq = hf * 4 + it * 8;
            const float* p = w2e + (size_t)(k0 + kq) * HID + gcol;
            float v0 = p[0], v1 = p[HID], v2 = p[2 * HID], v3 = p[3 * HID];
            ushort4 o;
            o.x = f2bf(v0); o.y = f2bf(v1); o.z = f2bf(v2); o.w = f2bf(v3);
            *reinterpret_cast<ushort4*>(&Bs[jcol][kq]) = o;
        }
        __syncthreads();
#pragma unroll
        for (int kk = 0; kk < 2; ++kk) {
            const int kb = kk * 32 + ((lane >> 4) << 3);
            bf16x8 a0 = *reinterpret_cast<const bf16x8*>(&As[w * 32 + (lane & 15)][kb]);
            bf16x8 a1 = *reinterpret_cast<const bf16x8*>(&As[w * 32 + 16 + (lane & 15)][kb]);
#pragma unroll
            for (int nf = 0; nf < 8; ++nf) {
                bf16x8 b = *reinterpret_cast<const bf16x8*>(&Bs[nf * 16 + (lane & 15)][kb]);
                acc[0][nf] = MFMA_BF16(a0, b, acc[0][nf]);
                acc[1][nf] = MFMA_BF16(a1, b, acc[1][nf]);
            }
        }
        __syncthreads();
    }
    const int rl0 = w * 32 + ((lane >> 4) << 2);
    const int cl  = lane & 15;
#pragma unroll
    for (int mf = 0; mf < 2; ++mf)
#pragma unroll
        for (int nf = 0; nf < 8; ++nf) {
            f32x4 v = acc[mf][nf];
#pragma unroll
            for (int r = 0; r < 4; ++r) {
                int row = rowbase + rl0 + mf * 16 + r;
                int col = nt * 128 + nf * 16 + cl;
                out[(size_t)row * HID + col] = v[r];
            }
        }
}

// ---------------- launch ----------------

extern "C" void kernel_launch(void* const* d_in, const int* in_sizes, int n_in,
                              void* d_out, int out_size, void* d_ws, size_t ws_size,
                              hipStream_t stream) {
    const float* X  = (const float*)d_in[0];
    const float* W1 = (const float*)d_in[1];
    const float* W2 = (const float*)d_in[2];
    float* out = (float*)d_out;

    const size_t XB_B  = (size_t)EXPERTS * TOK * HID * 2;        // 33.5 MB
    const size_t INT_B = (size_t)EXPERTS * TOK * INTER * 2;      // 92.3 MB
    const size_t need  = XB_B + INT_B;

    if (ws_size >= need) {
        unsigned short* Xb    = (unsigned short*)d_ws;
        unsigned short* inter = (unsigned short*)((char*)d_ws + XB_B);

        hipFuncSetAttribute((const void*)k_fc1_r6,
            hipFuncAttributeMaxDynamicSharedMemorySize, 73728);
        hipFuncSetAttribute((const void*)k_fc2_r6,
            hipFuncAttributeMaxDynamicSharedMemorySize, 73728);

        dim3 b256(256), b512(512);
        k_cvt_x <<<(EXPERTS * TOK * HID) / (256 * 8), b256, 0, stream>>>(X, Xb);
        k_fc1_r6<<<EXPERTS * 4 * (I2 / 128),  b512, 73728, stream>>>(Xb, W1, inter);
        k_fc2_r6<<<EXPERTS * 4 * (HID / 128), b512, 73728, stream>>>(inter, W2, out);
    } else {
        unsigned short* inter = (unsigned short*)d_ws;
        dim3 b256(256);
        k_fc1_glu_fb<<<EXPERTS * (TOK / BM) * (INTER / 64), b256, 0, stream>>>(X, W1, inter);
        k_fc2_fb    <<<EXPERTS * (TOK / BM) * (HID / 128),  b256, 0, stream>>>(inter, W2, out);
    }
}